// Round 11
// baseline (316.726 us; speedup 1.0000x reference)
//
#include <hip/hip_runtime.h>
#include <hip/hip_fp16.h>
#include <cstdint>
#include <cstddef>

#define NEG 0.2f
#define TILE 4096   // edges per partition tile
#define WEXP(e) __expf((e) > 0.f ? (e) : NEG * (e))

typedef int i4v __attribute__((ext_vector_type(4)));

__device__ __forceinline__ i4v ld_i4(const int* p) {   // dword-aligned 16B load
    i4v r;
    __builtin_memcpy(&r, p, 16);
    return r;
}
__device__ __forceinline__ __half2 bch(unsigned v) { __half2 r; *(unsigned*)&r = v; return r; }
__device__ __forceinline__ __half2 bchi(int v) { __half2 r; *(int*)&r = v; return r; }

// ---------------- Bucket histogram (LDS-privatized): bc[b] = #edges with dst in bucket b ----------------

__global__ __launch_bounds__(256) void bhist_k(const int* __restrict__ ei, int* __restrict__ bc, int E, int nbk) {
    __shared__ int sb[256];
    int t = threadIdx.x;
    sb[t] = 0;
    __syncthreads();
    int stride = gridDim.x * 256;
    for (int i = blockIdx.x * 256 + t; i < E; i += stride) {
        int d = __builtin_nontemporal_load(ei + E + i);
        atomicAdd(&sb[d >> 9], 1);
    }
    __syncthreads();
    if (t < nbk && sb[t] > 0) atomicAdd(&bc[t], sb[t]);
}

// ---------------- Bucket scan: bb[b] = exclusive scan of bc; curA[b] = bb[b]; bb[nbk] = E ----------------

__global__ __launch_bounds__(256) void bscan_k(const int* __restrict__ bc, int* __restrict__ bb,
                                               int* __restrict__ curA, int nbk) {
    __shared__ int sm[256];
    int t = threadIdx.x;
    int v = (t < nbk) ? bc[t] : 0;
    sm[t] = v; __syncthreads();
    for (int off = 1; off < 256; off <<= 1) {
        int u = (t >= off) ? sm[t - off] : 0;
        __syncthreads();
        sm[t] += u;
        __syncthreads();
    }
    if (t < nbk) {
        int ex = sm[t] - v;
        bb[t] = ex;
        curA[t] = ex;
        if (t == nbk - 1) bb[nbk] = sm[t];
    }
}

// ---------------- Phase A: LDS-staged partition of edges into 512-node buckets ----------------
// Block scan replaced by wave-shuffle scan (round-11): 6 shfl_up + 1 barrier vs 16 barriers.

__global__ __launch_bounds__(256) void partA_k(const int* __restrict__ ei, int* __restrict__ curA,
                                               uint2* __restrict__ pairs, int E, int nbk) {
    __shared__ int scnt[256];
    __shared__ int sbase[256];
    __shared__ int gbase[256];
    __shared__ int cur2[256];
    __shared__ int wsum[4];
    __shared__ int ssrc[TILE];
    __shared__ int sdst[TILE];
    int t = threadIdx.x;
    int lane = t & 63, wv = t >> 6;
    int ntiles = (E + TILE - 1) / TILE;
    for (int tile = blockIdx.x; tile < ntiles; tile += gridDim.x) {
        int base = tile * TILE;
        int cntE = min(TILE, E - base);
        scnt[t] = 0;
        __syncthreads();
        int mys[16], myd[16];
        #pragma unroll
        for (int j = 0; j < 16; j++) {
            int i = base + t + 256 * j;
            int s = 0, d = -1;
            if (i < E) {
                s = __builtin_nontemporal_load(ei + i);
                d = __builtin_nontemporal_load(ei + E + i);
            }
            mys[j] = s; myd[j] = d;
            if (d >= 0) atomicAdd(&scnt[d >> 9], 1);
        }
        __syncthreads();
        int v = scnt[t];
        int incl = v;
        #pragma unroll
        for (int off = 1; off < 64; off <<= 1) {
            int u = __shfl_up(incl, off);
            if (lane >= off) incl += u;
        }
        if (lane == 63) wsum[wv] = incl;
        __syncthreads();
        int wpre = 0;
        if (wv > 0) wpre += wsum[0];
        if (wv > 1) wpre += wsum[1];
        if (wv > 2) wpre += wsum[2];
        int myb = wpre + incl - v;      // exclusive within tile
        sbase[t] = myb;
        cur2[t] = myb;
        if (t < nbk && v > 0) gbase[t] = atomicAdd(&curA[t], v);
        __syncthreads();
        #pragma unroll
        for (int j = 0; j < 16; j++) {
            int d = myd[j];
            if (d >= 0) {
                int b = d >> 9;
                int pos = atomicAdd(&cur2[b], 1);
                ssrc[pos] = mys[j];
                sdst[pos] = d;
            }
        }
        __syncthreads();
        for (int i = t; i < cntE; i += 256) {
            int d = sdst[i];
            int b = d >> 9;
            int addr = gbase[b] + (i - sbase[b]);
            pairs[addr] = make_uint2((unsigned)ssrc[i], (unsigned)d);
        }
        __syncthreads();
    }
}

// ---------------- Phase B (two-pass): per-node count + wave-scan -> rp/cnt, then scatter ----------------

__global__ __launch_bounds__(256) void partB2_k(const uint2* __restrict__ pin, const int* __restrict__ bb,
                                                int* __restrict__ rp, int* __restrict__ cnt,
                                                int* __restrict__ srcout, int N) {
    __shared__ int cur[512];
    __shared__ int wsum[4];
    int b = blockIdx.x, t = threadIdx.x;
    int lane = t & 63, wv = t >> 6;
    int d0 = b << 9;
    cur[t] = 0; cur[t + 256] = 0;
    __syncthreads();
    int ebase = bb[b], eend = bb[b + 1];
    for (int j = ebase + t; j < eend; j += 256) {
        int d = (int)pin[j].y;
        atomicAdd(&cur[d - d0], 1);
    }
    __syncthreads();
    // thread t owns adjacent nodes 2t, 2t+1
    int v0 = cur[2 * t], v1 = cur[2 * t + 1];
    int s = v0 + v1;
    int incl = s;
    #pragma unroll
    for (int off = 1; off < 64; off <<= 1) {
        int u = __shfl_up(incl, off);
        if (lane >= off) incl += u;
    }
    if (lane == 63) wsum[wv] = incl;
    __syncthreads();
    int wpre = 0;
    if (wv > 0) wpre += wsum[0];
    if (wv > 1) wpre += wsum[1];
    if (wv > 2) wpre += wsum[2];
    int base0 = ebase + wpre + incl - s;
    int base1 = base0 + v0;
    int i0 = d0 + 2 * t, i1 = i0 + 1;
    if (i0 < N) { rp[i0] = base0; cnt[i0] = v0; }
    if (i1 < N) { rp[i1] = base1; cnt[i1] = v1; }
    cur[2 * t] = base0; cur[2 * t + 1] = base1;
    __syncthreads();
    for (int j = ebase + t; j < eend; j += 256) {
        uint2 p = pin[j];
        int d = (int)p.y;
        int pos = atomicAdd(&cur[d - d0], 1);
        srcout[pos] = (int)p.x;
    }
}

// ---------------- Layer 1 GEMM: h1 = x @ W1, fp16 k-pair LDS, VGPR-capped, single-tile blocks ----------------

__global__ __launch_bounds__(256, 4) void gemm1_k(const float* __restrict__ x, const float* __restrict__ W,
                                                  const float* __restrict__ a_src, const float* __restrict__ a_dst,
                                                  __half* __restrict__ h, float* __restrict__ alsrc,
                                                  float* __restrict__ aldst, int N) {
    __shared__ unsigned wh[64 * 64];   // 16 KB [k2][col]
    __shared__ unsigned xh[64 * 68];   // 17.4 KB [k2][row], pitch 68
    int t = threadIdx.x;
    for (int i = t; i < 4096; i += 256) {
        int k2 = i >> 6, col = i & 63;
        __half2 hv = __floats2half2_rn(W[(2 * k2) * 64 + col], W[(2 * k2 + 1) * 64 + col]);
        wh[i] = *(unsigned*)&hv;
    }
    int ct = t & 15, rt = t >> 4;
    int head = ct >> 2, cq = ct & 3;
    float asv[4], adv[4];
    #pragma unroll
    for (int j = 0; j < 4; j++) {
        asv[j] = a_src[head * 16 + 4 * cq + j];
        adv[j] = a_dst[head * 16 + 4 * cq + j];
    }
    int ntiles = (N + 63) >> 6;
    for (int tile = blockIdx.x; tile < ntiles; tile += gridDim.x) {
        int r0 = tile << 6;
        __syncthreads();
        #pragma unroll
        for (int p = 0; p < 8; p++) {
            int i = t + 256 * p;
            int f4i = i & 31, row = i >> 5;
            int r = r0 + row;
            float4 v = make_float4(0.f, 0.f, 0.f, 0.f);
            if (r < N) v = *(const float4*)(x + (size_t)r * 128 + 4 * f4i);
            __half2 p0 = __floats2half2_rn(v.x, v.y);
            __half2 p1 = __floats2half2_rn(v.z, v.w);
            xh[(2 * f4i) * 68 + row] = *(unsigned*)&p0;
            xh[(2 * f4i + 1) * 68 + row] = *(unsigned*)&p1;
        }
        __syncthreads();
        float acc[4][4];
        #pragma unroll
        for (int i = 0; i < 4; i++)
            #pragma unroll
            for (int j = 0; j < 4; j++) acc[i][j] = 0.f;
        __half2 hz = __float2half2_rn(0.f);
        for (int kc = 0; kc < 64; kc += 8) {
            __half2 ah[4][4];
            #pragma unroll
            for (int i = 0; i < 4; i++)
                #pragma unroll
                for (int j = 0; j < 4; j++) ah[i][j] = hz;
            #pragma unroll
            for (int j = 0; j < 8; j++) {
                int k2 = kc + j;
                uint4 wv = *(const uint4*)&wh[k2 * 64 + 4 * ct];
                uint4 xv = *(const uint4*)&xh[k2 * 68 + 4 * rt];
                __half2 w0 = bch(wv.x), w1 = bch(wv.y), w2 = bch(wv.z), w3 = bch(wv.w);
                __half2 x0 = bch(xv.x), x1 = bch(xv.y), x2 = bch(xv.z), x3 = bch(xv.w);
                ah[0][0] = __hfma2(x0, w0, ah[0][0]); ah[0][1] = __hfma2(x0, w1, ah[0][1]);
                ah[0][2] = __hfma2(x0, w2, ah[0][2]); ah[0][3] = __hfma2(x0, w3, ah[0][3]);
                ah[1][0] = __hfma2(x1, w0, ah[1][0]); ah[1][1] = __hfma2(x1, w1, ah[1][1]);
                ah[1][2] = __hfma2(x1, w2, ah[1][2]); ah[1][3] = __hfma2(x1, w3, ah[1][3]);
                ah[2][0] = __hfma2(x2, w0, ah[2][0]); ah[2][1] = __hfma2(x2, w1, ah[2][1]);
                ah[2][2] = __hfma2(x2, w2, ah[2][2]); ah[2][3] = __hfma2(x2, w3, ah[2][3]);
                ah[3][0] = __hfma2(x3, w0, ah[3][0]); ah[3][1] = __hfma2(x3, w1, ah[3][1]);
                ah[3][2] = __hfma2(x3, w2, ah[3][2]); ah[3][3] = __hfma2(x3, w3, ah[3][3]);
            }
            #pragma unroll
            for (int i = 0; i < 4; i++)
                #pragma unroll
                for (int j = 0; j < 4; j++) {
                    float2 q = __half22float2(ah[i][j]);
                    acc[i][j] += q.x + q.y;
                }
        }
        #pragma unroll
        for (int i = 0; i < 4; i++) {
            int r = r0 + 4 * rt + i;
            float ps = 0.f, pd = 0.f;
            #pragma unroll
            for (int j = 0; j < 4; j++) {
                ps = fmaf(acc[i][j], asv[j], ps);
                pd = fmaf(acc[i][j], adv[j], pd);
            }
            ps += __shfl_xor(ps, 1); ps += __shfl_xor(ps, 2);
            pd += __shfl_xor(pd, 1); pd += __shfl_xor(pd, 2);
            if (r < N) {
                __half2 h0 = __floats2half2_rn(acc[i][0], acc[i][1]);
                __half2 h1 = __floats2half2_rn(acc[i][2], acc[i][3]);
                *(__half2*)(h + (size_t)r * 64 + 4 * ct) = h0;
                *(__half2*)(h + (size_t)r * 64 + 4 * ct + 2) = h1;
                if (cq == 0) { alsrc[r * 4 + head] = ps; aldst[r * 4 + head] = pd; }
            }
        }
    }
}

// ---------------- prew: folded attention-logit weights + 4-col fp16 W2s table ----------------
// was/wad[k*4+h] = sum_c W2[k, h*32+c]*a_{src,dst}2[h,c]
// wkg4[cp4*128 + k2] = uint4{ h2(W(2k2,4cp4+q), W(2k2+1,4cp4+q)) : q=0..3 }
//   where W(k,col) = W2s[k][col] = W2[k&63][32*(k>>6)+col].

__global__ __launch_bounds__(256) void prew_k(const float* __restrict__ W2, const float* __restrict__ as2,
                                              const float* __restrict__ ad2, float* __restrict__ was,
                                              float* __restrict__ wad, uint4* __restrict__ wkg4) {
    int t = threadIdx.x;          // t = k*4 + h, k in [0,64), h in [0,4)
    int k = t >> 2, hh = t & 3;
    const float* wrow = W2 + k * 128 + hh * 32;
    const float* av = as2 + hh * 32;
    const float* dv = ad2 + hh * 32;
    float s = 0.f, ds = 0.f;
    #pragma unroll 8
    for (int c = 0; c < 32; c++) {
        float w = wrow[c];
        s = fmaf(w, av[c], s);
        ds = fmaf(w, dv[c], ds);
    }
    was[t] = s;
    wad[t] = ds;
    #pragma unroll
    for (int j = 0; j < 4; j++) {
        int e = t * 4 + j;
        int cp4 = e >> 7, k2 = e & 127;
        int h = k2 >> 5, kk = (2 * k2) & 63;
        const float* w0 = W2 + kk * 128 + h * 32;
        const float* w1 = W2 + (kk + 1) * 128 + h * 32;
        __half2 a0 = __floats2half2_rn(w0[4 * cp4 + 0], w1[4 * cp4 + 0]);
        __half2 a1 = __floats2half2_rn(w0[4 * cp4 + 1], w1[4 * cp4 + 1]);
        __half2 a2 = __floats2half2_rn(w0[4 * cp4 + 2], w1[4 * cp4 + 2]);
        __half2 a3 = __floats2half2_rn(w0[4 * cp4 + 3], w1[4 * cp4 + 3]);
        uint4 v;
        v.x = *(unsigned*)&a0; v.y = *(unsigned*)&a1;
        v.z = *(unsigned*)&a2; v.w = *(unsigned*)&a3;
        wkg4[e] = v;
    }
}

// ---------------- Layer 1 node aggregation + fused alv2 ----------------

__global__ __launch_bounds__(256) void node1_k(const __half* __restrict__ h, const int* __restrict__ srccol,
                                               const float* __restrict__ alsrc, const float* __restrict__ aldst,
                                               const int* __restrict__ rp, const int* __restrict__ cnt,
                                               const float* __restrict__ bias,
                                               const float* __restrict__ was, const float* __restrict__ wad,
                                               __half* __restrict__ out,
                                               float* __restrict__ alsrc2, float* __restrict__ aldst2, int N) {
    int t = threadIdx.x;
    int d = (blockIdx.x * 256 + t) >> 4;
    if (d >= N) return;
    int c = t & 15;
    int eh = c >> 2, hh = c & 3;   // lane evaluates (edge eh, head hh)
    int mh = c >> 2;               // lane's own dims belong to head mh
    const uint2* hb = (const uint2*)h;
    float myad = aldst[d * 4 + hh];
    float selfw = WEXP(alsrc[d * 4 + hh] + myad);
    __half2 sh2 = __float2half2_rn(selfw);
    int si = *(int*)&sh2;
    float mden = (eh == 0) ? selfw : 0.f;
    uint2 u = hb[((size_t)d << 4) + c];
    __half2 smy = bchi(__shfl(si, mh, 16));
    __half2 acc0 = __hmul2(smy, bch(u.x));
    __half2 acc1 = __hmul2(smy, bch(u.y));
    int start = rp[d], deg = cnt[d];
    int nq = deg >> 2;
    int i = 0;
    #define N1_PROC(G0, G1, G2, G3, AW) { \
        float w_ = WEXP((AW) + myad); \
        mden += w_; \
        __half2 wh_ = __float2half2_rn(w_); \
        int wi_ = *(int*)&wh_; \
        __half2 q0_ = bchi(__shfl(wi_, 0 + mh, 16)); \
        __half2 q1_ = bchi(__shfl(wi_, 4 + mh, 16)); \
        __half2 q2_ = bchi(__shfl(wi_, 8 + mh, 16)); \
        __half2 q3_ = bchi(__shfl(wi_, 12 + mh, 16)); \
        acc0 = __hfma2(q0_, bch(G0.x), acc0); acc1 = __hfma2(q0_, bch(G0.y), acc1); \
        acc0 = __hfma2(q1_, bch(G1.x), acc0); acc1 = __hfma2(q1_, bch(G1.y), acc1); \
        acc0 = __hfma2(q2_, bch(G2.x), acc0); acc1 = __hfma2(q2_, bch(G2.y), acc1); \
        acc0 = __hfma2(q3_, bch(G3.x), acc0); acc1 = __hfma2(q3_, bch(G3.y), acc1); }
    if (nq > 0) {
        i4v sv = ld_i4(srccol + start);
        uint2 g0 = hb[((size_t)(unsigned)sv.x << 4) + c];
        uint2 g1 = hb[((size_t)(unsigned)sv.y << 4) + c];
        uint2 g2 = hb[((size_t)(unsigned)sv.z << 4) + c];
        uint2 g3 = hb[((size_t)(unsigned)sv.w << 4) + c];
        int my = (eh == 0) ? sv.x : (eh == 1) ? sv.y : (eh == 2) ? sv.z : sv.w;
        float aw = alsrc[(size_t)my * 4 + hh];
        i4v nv = (nq > 1) ? ld_i4(srccol + start + 4) : sv;
        for (int q = 1; q < nq; q++) {
            uint2 n0 = hb[((size_t)(unsigned)nv.x << 4) + c];
            uint2 n1 = hb[((size_t)(unsigned)nv.y << 4) + c];
            uint2 n2 = hb[((size_t)(unsigned)nv.z << 4) + c];
            uint2 n3 = hb[((size_t)(unsigned)nv.w << 4) + c];
            int nmy = (eh == 0) ? nv.x : (eh == 1) ? nv.y : (eh == 2) ? nv.z : nv.w;
            float naw = alsrc[(size_t)nmy * 4 + hh];
            i4v nv2 = (q + 1 < nq) ? ld_i4(srccol + start + 4 * (q + 1)) : nv;
            N1_PROC(g0, g1, g2, g3, aw)
            g0 = n0; g1 = n1; g2 = n2; g3 = n3; aw = naw; nv = nv2;
        }
        N1_PROC(g0, g1, g2, g3, aw)
        i = nq << 2;
    }
    for (; i < deg; i++) {
        int s = srccol[start + i];
        uint2 us = hb[((size_t)(unsigned)s << 4) + c];
        float w = WEXP(alsrc[(size_t)s * 4 + hh] + myad);
        mden += (eh == 0) ? w : 0.f;
        __half2 wh = __float2half2_rn(w);
        int wi = *(int*)&wh;
        __half2 qq = bchi(__shfl(wi, mh, 16));
        acc0 = __hfma2(qq, bch(us.x), acc0);
        acc1 = __hfma2(qq, bch(us.y), acc1);
    }
    mden += __shfl_xor(mden, 4, 16);
    mden += __shfl_xor(mden, 8, 16);
    float den = __shfl(mden, mh, 16);
    float inv = 1.f / den;
    float2 f0 = __half22float2(acc0), f1 = __half22float2(acc1);
    float4 b = *(const float4*)(bias + 4 * c);
    float v0 = f0.x * inv + b.x, v1 = f0.y * inv + b.y;
    float v2 = f1.x * inv + b.z, v3 = f1.y * inv + b.w;
    __half2 o0 = __floats2half2_rn(v0, v1);
    __half2 o1 = __floats2half2_rn(v2, v3);
    uint2 o; o.x = *(unsigned*)&o0; o.y = *(unsigned*)&o1;
    *(uint2*)(out + (size_t)d * 64 + 4 * c) = o;
    // ---- fused alv2: alsrc2[d,h] = sum_k h1o[d,k]*was[k,h] ----
    const float4* was4 = (const float4*)was;
    const float4* wad4 = (const float4*)wad;
    float4 wa0 = was4[4 * c + 0], wa1 = was4[4 * c + 1], wa2 = was4[4 * c + 2], wa3 = was4[4 * c + 3];
    float4 wd0 = wad4[4 * c + 0], wd1 = wad4[4 * c + 1], wd2 = wad4[4 * c + 2], wd3 = wad4[4 * c + 3];
    float4 ps, pd;
    ps.x = fmaf(v0, wa0.x, fmaf(v1, wa1.x, fmaf(v2, wa2.x, v3 * wa3.x)));
    ps.y = fmaf(v0, wa0.y, fmaf(v1, wa1.y, fmaf(v2, wa2.y, v3 * wa3.y)));
    ps.z = fmaf(v0, wa0.z, fmaf(v1, wa1.z, fmaf(v2, wa2.z, v3 * wa3.z)));
    ps.w = fmaf(v0, wa0.w, fmaf(v1, wa1.w, fmaf(v2, wa2.w, v3 * wa3.w)));
    pd.x = fmaf(v0, wd0.x, fmaf(v1, wd1.x, fmaf(v2, wd2.x, v3 * wd3.x)));
    pd.y = fmaf(v0, wd0.y, fmaf(v1, wd1.y, fmaf(v2, wd2.y, v3 * wd3.y)));
    pd.z = fmaf(v0, wd0.z, fmaf(v1, wd1.z, fmaf(v2, wd2.z, v3 * wd3.z)));
    pd.w = fmaf(v0, wd0.w, fmaf(v1, wd1.w, fmaf(v2, wd2.w, v3 * wd3.w)));
    #pragma unroll
    for (int off = 1; off <= 8; off <<= 1) {
        ps.x += __shfl_xor(ps.x, off); ps.y += __shfl_xor(ps.y, off);
        ps.z += __shfl_xor(ps.z, off); ps.w += __shfl_xor(ps.w, off);
        pd.x += __shfl_xor(pd.x, off); pd.y += __shfl_xor(pd.y, off);
        pd.z += __shfl_xor(pd.z, off); pd.w += __shfl_xor(pd.w, off);
    }
    if (c == 0) {
        *(float4*)(alsrc2 + (size_t)d * 4) = ps;
        *(float4*)(aldst2 + (size_t)d * 4) = pd;
    }
}

// ---------------- Layer 2 node aggregation + fused output GEMM (k-split block-coop epilogue) ----------------
// Main loop unchanged. Epilogue: thread (n=t>>4, cp4=c&7, ks=c>>3) computes cols 4cp4..4cp4+3 for
// k-half ks: 16 y-b128 + 64 w-b128 (was 96); halves combined via shfl_xor(8); distributed softmax.

#define EDGE_SH(J, U) { \
    __half2 l_ = bch(U.x), h_ = bch(U.y); \
    __half2 qa = bchi(__shfl(wi, 4 * J + 0, 16)); \
    __half2 qb = bchi(__shfl(wi, 4 * J + 1, 16)); \
    __half2 qc = bchi(__shfl(wi, 4 * J + 2, 16)); \
    __half2 qd = bchi(__shfl(wi, 4 * J + 3, 16)); \
    aA0 = __hfma2(qa, l_, aA0); aA1 = __hfma2(qa, h_, aA1); \
    aB0 = __hfma2(qb, l_, aB0); aB1 = __hfma2(qb, h_, aB1); \
    aC0 = __hfma2(qc, l_, aC0); aC1 = __hfma2(qc, h_, aC1); \
    aD0 = __hfma2(qd, l_, aD0); aD1 = __hfma2(qd, h_, aD1); }

__global__ __launch_bounds__(256) void node2_k(const __half* __restrict__ h1o, const int* __restrict__ srccol,
                                               const float* __restrict__ alsrc, const float* __restrict__ aldst,
                                               const int* __restrict__ rp, const int* __restrict__ cnt,
                                               const uint4* __restrict__ wkg4, const float* __restrict__ b2,
                                               float* __restrict__ out, int N) {
    __shared__ unsigned wt[8 * 516];     // 16.5 KB [cp4][k2] uint4, pitch 516 unsigneds
    __shared__ unsigned ys[16 * 132];    // 8.4 KB [n][k2-pair], pitch 132
    int t = threadIdx.x;
    #pragma unroll
    for (int j = 0; j < 4; j++) {
        int i = t + 256 * j;             // i in [0,1024)
        int cp0 = i >> 7, k20 = i & 127;
        *(uint4*)&wt[cp0 * 516 + 4 * k20] = wkg4[i];
    }
    int d = blockIdx.x * 16 + (t >> 4);
    int c = t & 15;
    bool live = d < N;
    __half2 hz = __float2half2_rn(0.f);
    if (live) {
        int eh = c >> 2;      // edge slot this lane evaluates (0..3)
        int hh = c & 3;       // head this lane evaluates
        const uint2* hb = (const uint2*)h1o;           // 16 uint2 per 64-half row
        float myad = aldst[d * 4 + hh];
        float selfw = WEXP(alsrc[d * 4 + hh] + myad);
        __half2 selfh = __float2half2_rn(selfw);
        int selfi = *(int*)&selfh;
        float mden = (eh == 0) ? selfw : 0.f;
        uint2 u = hb[((size_t)d << 4) + c];
        __half2 lo = bch(u.x), hi = bch(u.y);
        __half2 sA = bchi(__shfl(selfi, 0, 16));
        __half2 sB = bchi(__shfl(selfi, 1, 16));
        __half2 sC = bchi(__shfl(selfi, 2, 16));
        __half2 sD = bchi(__shfl(selfi, 3, 16));
        __half2 aA0 = __hmul2(sA, lo), aA1 = __hmul2(sA, hi);
        __half2 aB0 = __hmul2(sB, lo), aB1 = __hmul2(sB, hi);
        __half2 aC0 = __hmul2(sC, lo), aC1 = __hmul2(sC, hi);
        __half2 aD0 = __hmul2(sD, lo), aD1 = __hmul2(sD, hi);
        int start = rp[d], deg = cnt[d];
        int nq = deg >> 2;
        int i = 0;
        #define N2_PROC(G0, G1, G2, G3, AW) { \
            float w_ = WEXP((AW) + myad); \
            mden += w_; \
            __half2 wh_ = __float2half2_rn(w_); \
            int wi = *(int*)&wh_; \
            EDGE_SH(0, G0) EDGE_SH(1, G1) EDGE_SH(2, G2) EDGE_SH(3, G3) }
        if (nq > 0) {
            i4v sv = ld_i4(srccol + start);
            uint2 g0 = hb[((size_t)(unsigned)sv.x << 4) + c];
            uint2 g1 = hb[((size_t)(unsigned)sv.y << 4) + c];
            uint2 g2 = hb[((size_t)(unsigned)sv.z << 4) + c];
            uint2 g3 = hb[((size_t)(unsigned)sv.w << 4) + c];
            int my = (eh == 0) ? sv.x : (eh == 1) ? sv.y : (eh == 2) ? sv.z : sv.w;
            float aw = alsrc[(size_t)my * 4 + hh];
            i4v nv = (nq > 1) ? ld_i4(srccol + start + 4) : sv;
            for (int q = 1; q < nq; q++) {
                uint2 n0 = hb[((size_t)(unsigned)nv.x << 4) + c];
                uint2 n1 = hb[((size_t)(unsigned)nv.y << 4) + c];
                uint2 n2 = hb[((size_t)(unsigned)nv.z << 4) + c];
                uint2 n3 = hb[((size_t)(unsigned)nv.w << 4) + c];
                int nmy = (eh == 0) ? nv.x : (eh == 1) ? nv.y : (eh == 2) ? nv.z : nv.w;
                float naw = alsrc[(size_t)nmy * 4 + hh];
                i4v nv2 = (q + 1 < nq) ? ld_i4(srccol + start + 4 * (q + 1)) : nv;
                N2_PROC(g0, g1, g2, g3, aw)
                g0 = n0; g1 = n1; g2 = n2; g3 = n3; aw = naw; nv = nv2;
            }
            N2_PROC(g0, g1, g2, g3, aw)
            i = nq << 2;
        }
        for (; i < deg; i++) {
            int s = srccol[start + i];
            uint2 us = hb[((size_t)(unsigned)s << 4) + c];
            float w = WEXP(alsrc[(size_t)s * 4 + hh] + myad);
            mden += (eh == 0) ? w : 0.f;
            __half2 wh = __float2half2_rn(w);
            int wi = *(int*)&wh;
            EDGE_SH(0, us)
        }
        mden += __shfl_xor(mden, 4, 16);
        mden += __shfl_xor(mden, 8, 16);
        float dnA = __shfl(mden, 0, 16);
        float dnB = __shfl(mden, 1, 16);
        float dnC = __shfl(mden, 2, 16);
        float dnD = __shfl(mden, 3, 16);
        __half2 jA = __float2half2_rn(0.25f / dnA), jB = __float2half2_rn(0.25f / dnB);
        __half2 jC = __float2half2_rn(0.25f / dnC), jD = __float2half2_rn(0.25f / dnD);
        __half2 y00 = __hmul2(jA, aA0), y01 = __hmul2(jA, aA1);
        __half2 y10 = __hmul2(jB, aB0), y11 = __hmul2(jB, aB1);
        __half2 y20 = __hmul2(jC, aC0), y21 = __hmul2(jC, aC1);
        __half2 y30 = __hmul2(jD, aD0), y31 = __hmul2(jD, aD1);
        // stage y to LDS: pair index p = 32h + 2c (+1)
        unsigned* yp = ys + (t >> 4) * 132 + 2 * c;
        *(uint2*)&yp[0]  = make_uint2(*(unsigned*)&y00, *(unsigned*)&y01);
        *(uint2*)&yp[32] = make_uint2(*(unsigned*)&y10, *(unsigned*)&y11);
        *(uint2*)&yp[64] = make_uint2(*(unsigned*)&y20, *(unsigned*)&y21);
        *(uint2*)&yp[96] = make_uint2(*(unsigned*)&y30, *(unsigned*)&y31);
    }
    __syncthreads();
    if (!live) return;
    int n = t >> 4;
    int cp4 = c & 7, ks = c >> 3;
    const unsigned* yr = ys + n * 132 + 64 * ks;
    const unsigned* wr = wt + cp4 * 516 + 256 * ks;
    float f0 = 0.f, f1 = 0.f, f2 = 0.f, f3 = 0.f;
    for (int kc = 0; kc < 64; kc += 16) {
        __half2 a0 = hz, a1 = hz, a2 = hz, a3 = hz;
        #pragma unroll
        for (int j = 0; j < 4; j++) {
            int p = kc + 4 * j;
            uint4 yv = *(const uint4*)&yr[p];
            uint4 w0 = *(const uint4*)&wr[4 * (p + 0)];
            uint4 w1 = *(const uint4*)&wr[4 * (p + 1)];
            uint4 w2 = *(const uint4*)&wr[4 * (p + 2)];
            uint4 w3 = *(const uint4*)&wr[4 * (p + 3)];
            __half2 yv0 = bch(yv.x), yv1 = bch(yv.y), yv2 = bch(yv.z), yv3 = bch(yv.w);
            a0 = __hfma2(yv0, bch(w0.x), a0); a1 = __hfma2(yv0, bch(w0.y), a1);
            a2 = __hfma2(yv0, bch(w0.z), a2); a3 = __hfma2(yv0, bch(w0.w), a3);
            a0 = __hfma2(yv1, bch(w1.x), a0); a1 = __hfma2(yv1, bch(w1.y), a1);
            a2 = __hfma2(yv1, bch(w1.z), a2); a3 = __hfma2(yv1, bch(w1.w), a3);
            a0 = __hfma2(yv2, bch(w2.x), a0); a1 = __hfma2(yv2, bch(w2.y), a1);
            a2 = __hfma2(yv2, bch(w2.z), a2); a3 = __hfma2(yv2, bch(w2.w), a3);
            a0 = __hfma2(yv3, bch(w3.x), a0); a1 = __hfma2(yv3, bch(w3.y), a1);
            a2 = __hfma2(yv3, bch(w3.z), a2); a3 = __hfma2(yv3, bch(w3.w), a3);
        }
        float2 q;
        q = __half22float2(a0); f0 += q.x + q.y;
        q = __half22float2(a1); f1 += q.x + q.y;
        q = __half22float2(a2); f2 += q.x + q.y;
        q = __half22float2(a3); f3 += q.x + q.y;
    }
    // combine k-halves (ks bit = lane bit 3 within 16-group)
    f0 += __shfl_xor(f0, 8, 16);
    f1 += __shfl_xor(f1, 8, 16);
    f2 += __shfl_xor(f2, 8, 16);
    f3 += __shfl_xor(f3, 8, 16);
    float4 b4 = *(const float4*)(b2 + 4 * cp4);
    float e0 = f0 + b4.x, e1 = f1 + b4.y, e2 = f2 + b4.z, e3 = f3 + b4.w;
    e0 = e0 > 0.f ? e0 : __expf(e0) - 1.f;
    e1 = e1 > 0.f ? e1 : __expf(e1) - 1.f;
    e2 = e2 > 0.f ? e2 : __expf(e2) - 1.f;
    e3 = e3 > 0.f ? e3 : __expf(e3) - 1.f;
    float mx = fmaxf(fmaxf(e0, e1), fmaxf(e2, e3));
    #pragma unroll
    for (int off = 1; off <= 4; off <<= 1) mx = fmaxf(mx, __shfl_xor(mx, off, 16));
    float sm = __expf(e0 - mx) + __expf(e1 - mx) + __expf(e2 - mx) + __expf(e3 - mx);
    #pragma unroll
    for (int off = 1; off <= 4; off <<= 1) sm += __shfl_xor(sm, off, 16);
    float ls = mx + __logf(sm);
    if (ks == 0) {
        float4 o;
        o.x = e0 - ls; o.y = e1 - ls; o.z = e2 - ls; o.w = e3 - ls;
        *(float4*)(out + (size_t)d * 32 + 4 * cp4) = o;
    }
}

// ---------------- launch ----------------

extern "C" void kernel_launch(void* const* d_in, const int* in_sizes, int n_in,
                              void* d_out, int out_size, void* d_ws, size_t ws_size,
                              hipStream_t stream) {
    const float* x   = (const float*)d_in[0];
    const int*   ei  = (const int*)d_in[1];
    const float* W1  = (const float*)d_in[2];
    const float* as1 = (const float*)d_in[3];
    const float* ad1 = (const float*)d_in[4];
    const float* b1  = (const float*)d_in[5];
    const float* W2  = (const float*)d_in[6];
    const float* as2 = (const float*)d_in[7];
    const float* ad2 = (const float*)d_in[8];
    const float* b2  = (const float*)d_in[9];
    float* out = (float*)d_out;
    int N = in_sizes[0] / 128;
    int E = in_sizes[1] / 2;

    char* base = (char*)d_ws;
    size_t off = 0;
    auto alloc = [&](size_t bytes) -> char* {
        char* p = base + off;
        off = (off + bytes + 255) & ~(size_t)255;
        return p;
    };
    __half* h1h   = (__half*)alloc((size_t)N * 64 * 2);
    __half* h1o   = (__half*)alloc((size_t)N * 64 * 2);
    uint2*  pairs = (uint2*)alloc((size_t)E * 8);
    float* alsrc1 = (float*)alloc((size_t)N * 4 * 4);
    float* aldst1 = (float*)alloc((size_t)N * 4 * 4);
    float* alsrc2 = (float*)alloc((size_t)N * 4 * 4);
    float* aldst2 = (float*)alloc((size_t)N * 4 * 4);
    float* was    = (float*)alloc(256 * 4);
    float* wad    = (float*)alloc(256 * 4);
    uint4* wkg4   = (uint4*)alloc(1024 * 16);
    int* cnt  = (int*)alloc((size_t)N * 4);
    int* rp   = (int*)alloc((size_t)N * 4);
    int* curA = (int*)alloc(256 * 4);
    int* bc   = (int*)alloc(256 * 4);
    int* bb   = (int*)alloc(260 * 4);
    int* srccol = (int*)alloc((size_t)E * 4);

    int nbk = (N + 511) >> 9;       // 512-node buckets
    int ntilesA = (E + TILE - 1) / TILE;
    int nt1 = (N + 63) >> 6;        // 64-row GEMM tiles

    prew_k<<<1, 256, 0, stream>>>(W2, as2, ad2, was, wad, wkg4);
    hipMemsetAsync(bc, 0, 256 * 4, stream);
    bhist_k<<<512, 256, 0, stream>>>(ei, bc, E, nbk);
    bscan_k<<<1, 256, 0, stream>>>(bc, bb, curA, nbk);
    partA_k<<<ntilesA, 256, 0, stream>>>(ei, curA, pairs, E, nbk);
    partB2_k<<<nbk, 256, 0, stream>>>(pairs, bb, rp, cnt, srccol, N);

    gemm1_k<<<nt1, 256, 0, stream>>>(x, W1, as1, ad1, h1h, alsrc1, aldst1, N);
    node1_k<<<(N + 15) / 16, 256, 0, stream>>>(h1h, srccol, alsrc1, aldst1, rp, cnt, b1,
                                               was, wad, h1o, alsrc2, aldst2, N);
    node2_k<<<(N + 15) / 16, 256, 0, stream>>>(h1o, srccol, alsrc2, aldst2, rp, cnt,
                                               wkg4, b2, out, N);
}

// Round 12
// 309.302 us; speedup vs baseline: 1.0240x; 1.0240x over previous
//
#include <hip/hip_runtime.h>
#include <hip/hip_fp16.h>
#include <cstdint>
#include <cstddef>

#define NEG 0.2f
#define TILE 4096   // edges per partition tile
#define WEXP(e) __expf((e) > 0.f ? (e) : NEG * (e))

typedef int i4v __attribute__((ext_vector_type(4)));

__device__ __forceinline__ i4v ld_i4(const int* p) {   // dword-aligned 16B load
    i4v r;
    __builtin_memcpy(&r, p, 16);
    return r;
}
__device__ __forceinline__ __half2 bch(unsigned v) { __half2 r; *(unsigned*)&r = v; return r; }
__device__ __forceinline__ __half2 bchi(int v) { __half2 r; *(int*)&r = v; return r; }

// ---------------- Bucket histogram (LDS-privatized): bc[b] = #edges with dst in bucket b ----------------

__global__ __launch_bounds__(256) void bhist_k(const int* __restrict__ ei, int* __restrict__ bc, int E, int nbk) {
    __shared__ int sb[256];
    int t = threadIdx.x;
    sb[t] = 0;
    __syncthreads();
    int stride = gridDim.x * 256;
    for (int i = blockIdx.x * 256 + t; i < E; i += stride) {
        int d = __builtin_nontemporal_load(ei + E + i);
        atomicAdd(&sb[d >> 9], 1);
    }
    __syncthreads();
    if (t < nbk && sb[t] > 0) atomicAdd(&bc[t], sb[t]);
}

// ---------------- Bucket scan: bb[b] = exclusive scan of bc; curA[b] = bb[b]; bb[nbk] = E ----------------

__global__ __launch_bounds__(256) void bscan_k(const int* __restrict__ bc, int* __restrict__ bb,
                                               int* __restrict__ curA, int nbk) {
    __shared__ int sm[256];
    int t = threadIdx.x;
    int v = (t < nbk) ? bc[t] : 0;
    sm[t] = v; __syncthreads();
    for (int off = 1; off < 256; off <<= 1) {
        int u = (t >= off) ? sm[t - off] : 0;
        __syncthreads();
        sm[t] += u;
        __syncthreads();
    }
    if (t < nbk) {
        int ex = sm[t] - v;
        bb[t] = ex;
        curA[t] = ex;
        if (t == nbk - 1) bb[nbk] = sm[t];
    }
}

// ---------------- Phase A: LDS-staged partition of edges into 512-node buckets ----------------
// Wave-shuffle scan (kept from round 11: measured ~-4us bundled with partB2/grid changes).

__global__ __launch_bounds__(256) void partA_k(const int* __restrict__ ei, int* __restrict__ curA,
                                               uint2* __restrict__ pairs, int E, int nbk) {
    __shared__ int scnt[256];
    __shared__ int sbase[256];
    __shared__ int gbase[256];
    __shared__ int cur2[256];
    __shared__ int wsum[4];
    __shared__ int ssrc[TILE];
    __shared__ int sdst[TILE];
    int t = threadIdx.x;
    int lane = t & 63, wv = t >> 6;
    int ntiles = (E + TILE - 1) / TILE;
    for (int tile = blockIdx.x; tile < ntiles; tile += gridDim.x) {
        int base = tile * TILE;
        int cntE = min(TILE, E - base);
        scnt[t] = 0;
        __syncthreads();
        int mys[16], myd[16];
        #pragma unroll
        for (int j = 0; j < 16; j++) {
            int i = base + t + 256 * j;
            int s = 0, d = -1;
            if (i < E) {
                s = __builtin_nontemporal_load(ei + i);
                d = __builtin_nontemporal_load(ei + E + i);
            }
            mys[j] = s; myd[j] = d;
            if (d >= 0) atomicAdd(&scnt[d >> 9], 1);
        }
        __syncthreads();
        int v = scnt[t];
        int incl = v;
        #pragma unroll
        for (int off = 1; off < 64; off <<= 1) {
            int u = __shfl_up(incl, off);
            if (lane >= off) incl += u;
        }
        if (lane == 63) wsum[wv] = incl;
        __syncthreads();
        int wpre = 0;
        if (wv > 0) wpre += wsum[0];
        if (wv > 1) wpre += wsum[1];
        if (wv > 2) wpre += wsum[2];
        int myb = wpre + incl - v;      // exclusive within tile
        sbase[t] = myb;
        cur2[t] = myb;
        if (t < nbk && v > 0) gbase[t] = atomicAdd(&curA[t], v);
        __syncthreads();
        #pragma unroll
        for (int j = 0; j < 16; j++) {
            int d = myd[j];
            if (d >= 0) {
                int b = d >> 9;
                int pos = atomicAdd(&cur2[b], 1);
                ssrc[pos] = mys[j];
                sdst[pos] = d;
            }
        }
        __syncthreads();
        for (int i = t; i < cntE; i += 256) {
            int d = sdst[i];
            int b = d >> 9;
            int addr = gbase[b] + (i - sbase[b]);
            pairs[addr] = make_uint2((unsigned)ssrc[i], (unsigned)d);
        }
        __syncthreads();
    }
}

// ---------------- Phase B (two-pass): per-node count + wave-scan -> rp/cnt, then scatter ----------------

__global__ __launch_bounds__(256) void partB2_k(const uint2* __restrict__ pin, const int* __restrict__ bb,
                                                int* __restrict__ rp, int* __restrict__ cnt,
                                                int* __restrict__ srcout, int N) {
    __shared__ int cur[512];
    __shared__ int wsum[4];
    int b = blockIdx.x, t = threadIdx.x;
    int lane = t & 63, wv = t >> 6;
    int d0 = b << 9;
    cur[t] = 0; cur[t + 256] = 0;
    __syncthreads();
    int ebase = bb[b], eend = bb[b + 1];
    for (int j = ebase + t; j < eend; j += 256) {
        int d = (int)pin[j].y;
        atomicAdd(&cur[d - d0], 1);
    }
    __syncthreads();
    // thread t owns adjacent nodes 2t, 2t+1
    int v0 = cur[2 * t], v1 = cur[2 * t + 1];
    int s = v0 + v1;
    int incl = s;
    #pragma unroll
    for (int off = 1; off < 64; off <<= 1) {
        int u = __shfl_up(incl, off);
        if (lane >= off) incl += u;
    }
    if (lane == 63) wsum[wv] = incl;
    __syncthreads();
    int wpre = 0;
    if (wv > 0) wpre += wsum[0];
    if (wv > 1) wpre += wsum[1];
    if (wv > 2) wpre += wsum[2];
    int base0 = ebase + wpre + incl - s;
    int base1 = base0 + v0;
    int i0 = d0 + 2 * t, i1 = i0 + 1;
    if (i0 < N) { rp[i0] = base0; cnt[i0] = v0; }
    if (i1 < N) { rp[i1] = base1; cnt[i1] = v1; }
    cur[2 * t] = base0; cur[2 * t + 1] = base1;
    __syncthreads();
    for (int j = ebase + t; j < eend; j += 256) {
        uint2 p = pin[j];
        int d = (int)p.y;
        int pos = atomicAdd(&cur[d - d0], 1);
        srcout[pos] = (int)p.x;
    }
}

// ---------------- Layer 1 GEMM: h1 = x @ W1, fp16 k-pair LDS, VGPR-capped, single-tile blocks ----------------

__global__ __launch_bounds__(256, 4) void gemm1_k(const float* __restrict__ x, const float* __restrict__ W,
                                                  const float* __restrict__ a_src, const float* __restrict__ a_dst,
                                                  __half* __restrict__ h, float* __restrict__ alsrc,
                                                  float* __restrict__ aldst, int N) {
    __shared__ unsigned wh[64 * 64];   // 16 KB [k2][col]
    __shared__ unsigned xh[64 * 68];   // 17.4 KB [k2][row], pitch 68
    int t = threadIdx.x;
    for (int i = t; i < 4096; i += 256) {
        int k2 = i >> 6, col = i & 63;
        __half2 hv = __floats2half2_rn(W[(2 * k2) * 64 + col], W[(2 * k2 + 1) * 64 + col]);
        wh[i] = *(unsigned*)&hv;
    }
    int ct = t & 15, rt = t >> 4;
    int head = ct >> 2, cq = ct & 3;
    float asv[4], adv[4];
    #pragma unroll
    for (int j = 0; j < 4; j++) {
        asv[j] = a_src[head * 16 + 4 * cq + j];
        adv[j] = a_dst[head * 16 + 4 * cq + j];
    }
    int ntiles = (N + 63) >> 6;
    for (int tile = blockIdx.x; tile < ntiles; tile += gridDim.x) {
        int r0 = tile << 6;
        __syncthreads();
        #pragma unroll
        for (int p = 0; p < 8; p++) {
            int i = t + 256 * p;
            int f4i = i & 31, row = i >> 5;
            int r = r0 + row;
            float4 v = make_float4(0.f, 0.f, 0.f, 0.f);
            if (r < N) v = *(const float4*)(x + (size_t)r * 128 + 4 * f4i);
            __half2 p0 = __floats2half2_rn(v.x, v.y);
            __half2 p1 = __floats2half2_rn(v.z, v.w);
            xh[(2 * f4i) * 68 + row] = *(unsigned*)&p0;
            xh[(2 * f4i + 1) * 68 + row] = *(unsigned*)&p1;
        }
        __syncthreads();
        float acc[4][4];
        #pragma unroll
        for (int i = 0; i < 4; i++)
            #pragma unroll
            for (int j = 0; j < 4; j++) acc[i][j] = 0.f;
        __half2 hz = __float2half2_rn(0.f);
        for (int kc = 0; kc < 64; kc += 8) {
            __half2 ah[4][4];
            #pragma unroll
            for (int i = 0; i < 4; i++)
                #pragma unroll
                for (int j = 0; j < 4; j++) ah[i][j] = hz;
            #pragma unroll
            for (int j = 0; j < 8; j++) {
                int k2 = kc + j;
                uint4 wv = *(const uint4*)&wh[k2 * 64 + 4 * ct];
                uint4 xv = *(const uint4*)&xh[k2 * 68 + 4 * rt];
                __half2 w0 = bch(wv.x), w1 = bch(wv.y), w2 = bch(wv.z), w3 = bch(wv.w);
                __half2 x0 = bch(xv.x), x1 = bch(xv.y), x2 = bch(xv.z), x3 = bch(xv.w);
                ah[0][0] = __hfma2(x0, w0, ah[0][0]); ah[0][1] = __hfma2(x0, w1, ah[0][1]);
                ah[0][2] = __hfma2(x0, w2, ah[0][2]); ah[0][3] = __hfma2(x0, w3, ah[0][3]);
                ah[1][0] = __hfma2(x1, w0, ah[1][0]); ah[1][1] = __hfma2(x1, w1, ah[1][1]);
                ah[1][2] = __hfma2(x1, w2, ah[1][2]); ah[1][3] = __hfma2(x1, w3, ah[1][3]);
                ah[2][0] = __hfma2(x2, w0, ah[2][0]); ah[2][1] = __hfma2(x2, w1, ah[2][1]);
                ah[2][2] = __hfma2(x2, w2, ah[2][2]); ah[2][3] = __hfma2(x2, w3, ah[2][3]);
                ah[3][0] = __hfma2(x3, w0, ah[3][0]); ah[3][1] = __hfma2(x3, w1, ah[3][1]);
                ah[3][2] = __hfma2(x3, w2, ah[3][2]); ah[3][3] = __hfma2(x3, w3, ah[3][3]);
            }
            #pragma unroll
            for (int i = 0; i < 4; i++)
                #pragma unroll
                for (int j = 0; j < 4; j++) {
                    float2 q = __half22float2(ah[i][j]);
                    acc[i][j] += q.x + q.y;
                }
        }
        #pragma unroll
        for (int i = 0; i < 4; i++) {
            int r = r0 + 4 * rt + i;
            float ps = 0.f, pd = 0.f;
            #pragma unroll
            for (int j = 0; j < 4; j++) {
                ps = fmaf(acc[i][j], asv[j], ps);
                pd = fmaf(acc[i][j], adv[j], pd);
            }
            ps += __shfl_xor(ps, 1); ps += __shfl_xor(ps, 2);
            pd += __shfl_xor(pd, 1); pd += __shfl_xor(pd, 2);
            if (r < N) {
                __half2 h0 = __floats2half2_rn(acc[i][0], acc[i][1]);
                __half2 h1 = __floats2half2_rn(acc[i][2], acc[i][3]);
                *(__half2*)(h + (size_t)r * 64 + 4 * ct) = h0;
                *(__half2*)(h + (size_t)r * 64 + 4 * ct + 2) = h1;
                if (cq == 0) { alsrc[r * 4 + head] = ps; aldst[r * 4 + head] = pd; }
            }
        }
    }
}

// ---------------- prew: folded attention-logit weights + column-pair fp16 W2s table (round-10 layout) ----------------
// wkg[cp*128 + k2] = uint2{ half2(W(2k2,2cp), W(2k2+1,2cp)), half2(W(2k2,2cp+1), W(2k2+1,2cp+1)) }

__global__ __launch_bounds__(256) void prew_k(const float* __restrict__ W2, const float* __restrict__ as2,
                                              const float* __restrict__ ad2, float* __restrict__ was,
                                              float* __restrict__ wad, uint2* __restrict__ wkg) {
    int t = threadIdx.x;          // t = k*4 + h, k in [0,64), h in [0,4)
    int k = t >> 2, hh = t & 3;
    const float* wrow = W2 + k * 128 + hh * 32;
    const float* av = as2 + hh * 32;
    const float* dv = ad2 + hh * 32;
    float s = 0.f, ds = 0.f;
    #pragma unroll 8
    for (int c = 0; c < 32; c++) {
        float w = wrow[c];
        s = fmaf(w, av[c], s);
        ds = fmaf(w, dv[c], ds);
    }
    was[t] = s;
    wad[t] = ds;
    #pragma unroll
    for (int j = 0; j < 8; j++) {
        int e = t * 8 + j;
        int cp = e >> 7, k2 = e & 127;
        int h = k2 >> 5, kk = (2 * k2) & 63;
        const float* w0 = W2 + kk * 128 + h * 32;
        const float* w1 = W2 + (kk + 1) * 128 + h * 32;
        __half2 hx = __floats2half2_rn(w0[2 * cp], w1[2 * cp]);
        __half2 hy = __floats2half2_rn(w0[2 * cp + 1], w1[2 * cp + 1]);
        uint2 v;
        v.x = *(unsigned*)&hx;
        v.y = *(unsigned*)&hy;
        wkg[e] = v;
    }
}

// ---------------- Layer 1 node aggregation + fused alv2 ----------------

__global__ __launch_bounds__(256) void node1_k(const __half* __restrict__ h, const int* __restrict__ srccol,
                                               const float* __restrict__ alsrc, const float* __restrict__ aldst,
                                               const int* __restrict__ rp, const int* __restrict__ cnt,
                                               const float* __restrict__ bias,
                                               const float* __restrict__ was, const float* __restrict__ wad,
                                               __half* __restrict__ out,
                                               float* __restrict__ alsrc2, float* __restrict__ aldst2, int N) {
    int t = threadIdx.x;
    int d = (blockIdx.x * 256 + t) >> 4;
    if (d >= N) return;
    int c = t & 15;
    int eh = c >> 2, hh = c & 3;   // lane evaluates (edge eh, head hh)
    int mh = c >> 2;               // lane's own dims belong to head mh
    const uint2* hb = (const uint2*)h;
    float myad = aldst[d * 4 + hh];
    float selfw = WEXP(alsrc[d * 4 + hh] + myad);
    __half2 sh2 = __float2half2_rn(selfw);
    int si = *(int*)&sh2;
    float mden = (eh == 0) ? selfw : 0.f;
    uint2 u = hb[((size_t)d << 4) + c];
    __half2 smy = bchi(__shfl(si, mh, 16));
    __half2 acc0 = __hmul2(smy, bch(u.x));
    __half2 acc1 = __hmul2(smy, bch(u.y));
    int start = rp[d], deg = cnt[d];
    int nq = deg >> 2;
    int i = 0;
    #define N1_PROC(G0, G1, G2, G3, AW) { \
        float w_ = WEXP((AW) + myad); \
        mden += w_; \
        __half2 wh_ = __float2half2_rn(w_); \
        int wi_ = *(int*)&wh_; \
        __half2 q0_ = bchi(__shfl(wi_, 0 + mh, 16)); \
        __half2 q1_ = bchi(__shfl(wi_, 4 + mh, 16)); \
        __half2 q2_ = bchi(__shfl(wi_, 8 + mh, 16)); \
        __half2 q3_ = bchi(__shfl(wi_, 12 + mh, 16)); \
        acc0 = __hfma2(q0_, bch(G0.x), acc0); acc1 = __hfma2(q0_, bch(G0.y), acc1); \
        acc0 = __hfma2(q1_, bch(G1.x), acc0); acc1 = __hfma2(q1_, bch(G1.y), acc1); \
        acc0 = __hfma2(q2_, bch(G2.x), acc0); acc1 = __hfma2(q2_, bch(G2.y), acc1); \
        acc0 = __hfma2(q3_, bch(G3.x), acc0); acc1 = __hfma2(q3_, bch(G3.y), acc1); }
    if (nq > 0) {
        i4v sv = ld_i4(srccol + start);
        uint2 g0 = hb[((size_t)(unsigned)sv.x << 4) + c];
        uint2 g1 = hb[((size_t)(unsigned)sv.y << 4) + c];
        uint2 g2 = hb[((size_t)(unsigned)sv.z << 4) + c];
        uint2 g3 = hb[((size_t)(unsigned)sv.w << 4) + c];
        int my = (eh == 0) ? sv.x : (eh == 1) ? sv.y : (eh == 2) ? sv.z : sv.w;
        float aw = alsrc[(size_t)my * 4 + hh];
        i4v nv = (nq > 1) ? ld_i4(srccol + start + 4) : sv;
        for (int q = 1; q < nq; q++) {
            uint2 n0 = hb[((size_t)(unsigned)nv.x << 4) + c];
            uint2 n1 = hb[((size_t)(unsigned)nv.y << 4) + c];
            uint2 n2 = hb[((size_t)(unsigned)nv.z << 4) + c];
            uint2 n3 = hb[((size_t)(unsigned)nv.w << 4) + c];
            int nmy = (eh == 0) ? nv.x : (eh == 1) ? nv.y : (eh == 2) ? nv.z : nv.w;
            float naw = alsrc[(size_t)nmy * 4 + hh];
            i4v nv2 = (q + 1 < nq) ? ld_i4(srccol + start + 4 * (q + 1)) : nv;
            N1_PROC(g0, g1, g2, g3, aw)
            g0 = n0; g1 = n1; g2 = n2; g3 = n3; aw = naw; nv = nv2;
        }
        N1_PROC(g0, g1, g2, g3, aw)
        i = nq << 2;
    }
    for (; i < deg; i++) {
        int s = srccol[start + i];
        uint2 us = hb[((size_t)(unsigned)s << 4) + c];
        float w = WEXP(alsrc[(size_t)s * 4 + hh] + myad);
        mden += (eh == 0) ? w : 0.f;
        __half2 wh = __float2half2_rn(w);
        int wi = *(int*)&wh;
        __half2 qq = bchi(__shfl(wi, mh, 16));
        acc0 = __hfma2(qq, bch(us.x), acc0);
        acc1 = __hfma2(qq, bch(us.y), acc1);
    }
    mden += __shfl_xor(mden, 4, 16);
    mden += __shfl_xor(mden, 8, 16);
    float den = __shfl(mden, mh, 16);
    float inv = 1.f / den;
    float2 f0 = __half22float2(acc0), f1 = __half22float2(acc1);
    float4 b = *(const float4*)(bias + 4 * c);
    float v0 = f0.x * inv + b.x, v1 = f0.y * inv + b.y;
    float v2 = f1.x * inv + b.z, v3 = f1.y * inv + b.w;
    __half2 o0 = __floats2half2_rn(v0, v1);
    __half2 o1 = __floats2half2_rn(v2, v3);
    uint2 o; o.x = *(unsigned*)&o0; o.y = *(unsigned*)&o1;
    *(uint2*)(out + (size_t)d * 64 + 4 * c) = o;
    // ---- fused alv2: alsrc2[d,h] = sum_k h1o[d,k]*was[k,h] ----
    const float4* was4 = (const float4*)was;
    const float4* wad4 = (const float4*)wad;
    float4 wa0 = was4[4 * c + 0], wa1 = was4[4 * c + 1], wa2 = was4[4 * c + 2], wa3 = was4[4 * c + 3];
    float4 wd0 = wad4[4 * c + 0], wd1 = wad4[4 * c + 1], wd2 = wad4[4 * c + 2], wd3 = wad4[4 * c + 3];
    float4 ps, pd;
    ps.x = fmaf(v0, wa0.x, fmaf(v1, wa1.x, fmaf(v2, wa2.x, v3 * wa3.x)));
    ps.y = fmaf(v0, wa0.y, fmaf(v1, wa1.y, fmaf(v2, wa2.y, v3 * wa3.y)));
    ps.z = fmaf(v0, wa0.z, fmaf(v1, wa1.z, fmaf(v2, wa2.z, v3 * wa3.z)));
    ps.w = fmaf(v0, wa0.w, fmaf(v1, wa1.w, fmaf(v2, wa2.w, v3 * wa3.w)));
    pd.x = fmaf(v0, wd0.x, fmaf(v1, wd1.x, fmaf(v2, wd2.x, v3 * wd3.x)));
    pd.y = fmaf(v0, wd0.y, fmaf(v1, wd1.y, fmaf(v2, wd2.y, v3 * wd3.y)));
    pd.z = fmaf(v0, wd0.z, fmaf(v1, wd1.z, fmaf(v2, wd2.z, v3 * wd3.z)));
    pd.w = fmaf(v0, wd0.w, fmaf(v1, wd1.w, fmaf(v2, wd2.w, v3 * wd3.w)));
    #pragma unroll
    for (int off = 1; off <= 8; off <<= 1) {
        ps.x += __shfl_xor(ps.x, off); ps.y += __shfl_xor(ps.y, off);
        ps.z += __shfl_xor(ps.z, off); ps.w += __shfl_xor(ps.w, off);
        pd.x += __shfl_xor(pd.x, off); pd.y += __shfl_xor(pd.y, off);
        pd.z += __shfl_xor(pd.z, off); pd.w += __shfl_xor(pd.w, off);
    }
    if (c == 0) {
        *(float4*)(alsrc2 + (size_t)d * 4) = ps;
        *(float4*)(aldst2 + (size_t)d * 4) = pd;
    }
}

// ---------------- Layer 2 node aggregation + fused output GEMM (round-10 block-coop epilogue) ----------------
// Conflict-free: wt[cp][k2] pitch 260, thread (n=t>>4, cp=t&15) computes out[d][2cp..2cp+1].

#define EDGE_SH(J, U) { \
    __half2 l_ = bch(U.x), h_ = bch(U.y); \
    __half2 qa = bchi(__shfl(wi, 4 * J + 0, 16)); \
    __half2 qb = bchi(__shfl(wi, 4 * J + 1, 16)); \
    __half2 qc = bchi(__shfl(wi, 4 * J + 2, 16)); \
    __half2 qd = bchi(__shfl(wi, 4 * J + 3, 16)); \
    aA0 = __hfma2(qa, l_, aA0); aA1 = __hfma2(qa, h_, aA1); \
    aB0 = __hfma2(qb, l_, aB0); aB1 = __hfma2(qb, h_, aB1); \
    aC0 = __hfma2(qc, l_, aC0); aC1 = __hfma2(qc, h_, aC1); \
    aD0 = __hfma2(qd, l_, aD0); aD1 = __hfma2(qd, h_, aD1); }

__global__ __launch_bounds__(256) void node2_k(const __half* __restrict__ h1o, const int* __restrict__ srccol,
                                               const float* __restrict__ alsrc, const float* __restrict__ aldst,
                                               const int* __restrict__ rp, const int* __restrict__ cnt,
                                               const uint2* __restrict__ wkg, const float* __restrict__ b2,
                                               float* __restrict__ out, int N) {
    __shared__ unsigned wt[16 * 260];    // 16.6 KB [cp][k2] uint2-pairs, pitch 260 unsigneds
    __shared__ unsigned ys[16 * 132];    // 8.4 KB [n][k2-pair], pitch 132
    int t = threadIdx.x;
    #pragma unroll
    for (int j = 0; j < 8; j++) {
        int i = t + 256 * j;
        int cp0 = i >> 7, k20 = i & 127;
        *(uint2*)&wt[cp0 * 260 + 2 * k20] = wkg[i];
    }
    int d = blockIdx.x * 16 + (t >> 4);
    int c = t & 15;
    bool live = d < N;
    __half2 hz = __float2half2_rn(0.f);
    if (live) {
        int eh = c >> 2;      // edge slot this lane evaluates (0..3)
        int hh = c & 3;       // head this lane evaluates
        const uint2* hb = (const uint2*)h1o;           // 16 uint2 per 64-half row
        float myad = aldst[d * 4 + hh];
        float selfw = WEXP(alsrc[d * 4 + hh] + myad);
        __half2 selfh = __float2half2_rn(selfw);
        int selfi = *(int*)&selfh;
        float mden = (eh == 0) ? selfw : 0.f;
        uint2 u = hb[((size_t)d << 4) + c];
        __half2 lo = bch(u.x), hi = bch(u.y);
        __half2 sA = bchi(__shfl(selfi, 0, 16));
        __half2 sB = bchi(__shfl(selfi, 1, 16));
        __half2 sC = bchi(__shfl(selfi, 2, 16));
        __half2 sD = bchi(__shfl(selfi, 3, 16));
        __half2 aA0 = __hmul2(sA, lo), aA1 = __hmul2(sA, hi);
        __half2 aB0 = __hmul2(sB, lo), aB1 = __hmul2(sB, hi);
        __half2 aC0 = __hmul2(sC, lo), aC1 = __hmul2(sC, hi);
        __half2 aD0 = __hmul2(sD, lo), aD1 = __hmul2(sD, hi);
        int start = rp[d], deg = cnt[d];
        int nq = deg >> 2;
        int i = 0;
        #define N2_PROC(G0, G1, G2, G3, AW) { \
            float w_ = WEXP((AW) + myad); \
            mden += w_; \
            __half2 wh_ = __float2half2_rn(w_); \
            int wi = *(int*)&wh_; \
            EDGE_SH(0, G0) EDGE_SH(1, G1) EDGE_SH(2, G2) EDGE_SH(3, G3) }
        if (nq > 0) {
            i4v sv = ld_i4(srccol + start);
            uint2 g0 = hb[((size_t)(unsigned)sv.x << 4) + c];
            uint2 g1 = hb[((size_t)(unsigned)sv.y << 4) + c];
            uint2 g2 = hb[((size_t)(unsigned)sv.z << 4) + c];
            uint2 g3 = hb[((size_t)(unsigned)sv.w << 4) + c];
            int my = (eh == 0) ? sv.x : (eh == 1) ? sv.y : (eh == 2) ? sv.z : sv.w;
            float aw = alsrc[(size_t)my * 4 + hh];
            i4v nv = (nq > 1) ? ld_i4(srccol + start + 4) : sv;
            for (int q = 1; q < nq; q++) {
                uint2 n0 = hb[((size_t)(unsigned)nv.x << 4) + c];
                uint2 n1 = hb[((size_t)(unsigned)nv.y << 4) + c];
                uint2 n2 = hb[((size_t)(unsigned)nv.z << 4) + c];
                uint2 n3 = hb[((size_t)(unsigned)nv.w << 4) + c];
                int nmy = (eh == 0) ? nv.x : (eh == 1) ? nv.y : (eh == 2) ? nv.z : nv.w;
                float naw = alsrc[(size_t)nmy * 4 + hh];
                i4v nv2 = (q + 1 < nq) ? ld_i4(srccol + start + 4 * (q + 1)) : nv;
                N2_PROC(g0, g1, g2, g3, aw)
                g0 = n0; g1 = n1; g2 = n2; g3 = n3; aw = naw; nv = nv2;
            }
            N2_PROC(g0, g1, g2, g3, aw)
            i = nq << 2;
        }
        for (; i < deg; i++) {
            int s = srccol[start + i];
            uint2 us = hb[((size_t)(unsigned)s << 4) + c];
            float w = WEXP(alsrc[(size_t)s * 4 + hh] + myad);
            mden += (eh == 0) ? w : 0.f;
            __half2 wh = __float2half2_rn(w);
            int wi = *(int*)&wh;
            EDGE_SH(0, us)
        }
        mden += __shfl_xor(mden, 4, 16);
        mden += __shfl_xor(mden, 8, 16);
        float dnA = __shfl(mden, 0, 16);
        float dnB = __shfl(mden, 1, 16);
        float dnC = __shfl(mden, 2, 16);
        float dnD = __shfl(mden, 3, 16);
        __half2 jA = __float2half2_rn(0.25f / dnA), jB = __float2half2_rn(0.25f / dnB);
        __half2 jC = __float2half2_rn(0.25f / dnC), jD = __float2half2_rn(0.25f / dnD);
        __half2 y00 = __hmul2(jA, aA0), y01 = __hmul2(jA, aA1);
        __half2 y10 = __hmul2(jB, aB0), y11 = __hmul2(jB, aB1);
        __half2 y20 = __hmul2(jC, aC0), y21 = __hmul2(jC, aC1);
        __half2 y30 = __hmul2(jD, aD0), y31 = __hmul2(jD, aD1);
        // stage y to LDS: pair index p = 32h + 2c (+1)
        unsigned* yp = ys + (t >> 4) * 132 + 2 * c;
        *(uint2*)&yp[0]  = make_uint2(*(unsigned*)&y00, *(unsigned*)&y01);
        *(uint2*)&yp[32] = make_uint2(*(unsigned*)&y10, *(unsigned*)&y11);
        *(uint2*)&yp[64] = make_uint2(*(unsigned*)&y20, *(unsigned*)&y21);
        *(uint2*)&yp[96] = make_uint2(*(unsigned*)&y30, *(unsigned*)&y31);
    }
    __syncthreads();
    if (!live) return;
    int n = t >> 4, cp = c;
    const unsigned* yr = ys + n * 132;
    const unsigned* wr = wt + cp * 260;
    float f0 = 0.f, f1 = 0.f;
    for (int kc = 0; kc < 128; kc += 16) {
        __half2 a0 = hz, a1 = hz;
        #pragma unroll
        for (int j = 0; j < 4; j++) {
            int k2 = kc + 4 * j;
            uint4 yv = *(const uint4*)&yr[k2];
            uint4 w0 = *(const uint4*)&wr[2 * k2];
            uint4 w1 = *(const uint4*)&wr[2 * k2 + 4];
            a0 = __hfma2(bch(yv.x), bch(w0.x), a0); a1 = __hfma2(bch(yv.x), bch(w0.y), a1);
            a0 = __hfma2(bch(yv.y), bch(w0.z), a0); a1 = __hfma2(bch(yv.y), bch(w0.w), a1);
            a0 = __hfma2(bch(yv.z), bch(w1.x), a0); a1 = __hfma2(bch(yv.z), bch(w1.y), a1);
            a0 = __hfma2(bch(yv.w), bch(w1.z), a0); a1 = __hfma2(bch(yv.w), bch(w1.w), a1);
        }
        float2 q0 = __half22float2(a0), q1 = __half22float2(a1);
        f0 += q0.x + q0.y;
        f1 += q1.x + q1.y;
    }
    float e0 = f0 + b2[2 * cp];
    float e1 = f1 + b2[2 * cp + 1];
    e0 = e0 > 0.f ? e0 : __expf(e0) - 1.f;
    e1 = e1 > 0.f ? e1 : __expf(e1) - 1.f;
    float mx = fmaxf(e0, e1);
    #pragma unroll
    for (int off = 1; off <= 8; off <<= 1) mx = fmaxf(mx, __shfl_xor(mx, off, 16));
    float sm = __expf(e0 - mx) + __expf(e1 - mx);
    #pragma unroll
    for (int off = 1; off <= 8; off <<= 1) sm += __shfl_xor(sm, off, 16);
    float ls = mx + __logf(sm);
    float2 ov = make_float2(e0 - ls, e1 - ls);
    *(float2*)(out + (size_t)d * 32 + 2 * cp) = ov;
}

// ---------------- launch ----------------

extern "C" void kernel_launch(void* const* d_in, const int* in_sizes, int n_in,
                              void* d_out, int out_size, void* d_ws, size_t ws_size,
                              hipStream_t stream) {
    const float* x   = (const float*)d_in[0];
    const int*   ei  = (const int*)d_in[1];
    const float* W1  = (const float*)d_in[2];
    const float* as1 = (const float*)d_in[3];
    const float* ad1 = (const float*)d_in[4];
    const float* b1  = (const float*)d_in[5];
    const float* W2  = (const float*)d_in[6];
    const float* as2 = (const float*)d_in[7];
    const float* ad2 = (const float*)d_in[8];
    const float* b2  = (const float*)d_in[9];
    float* out = (float*)d_out;
    int N = in_sizes[0] / 128;
    int E = in_sizes[1] / 2;

    char* base = (char*)d_ws;
    size_t off = 0;
    auto alloc = [&](size_t bytes) -> char* {
        char* p = base + off;
        off = (off + bytes + 255) & ~(size_t)255;
        return p;
    };
    __half* h1h   = (__half*)alloc((size_t)N * 64 * 2);
    __half* h1o   = (__half*)alloc((size_t)N * 64 * 2);
    uint2*  pairs = (uint2*)alloc((size_t)E * 8);
    float* alsrc1 = (float*)alloc((size_t)N * 4 * 4);
    float* aldst1 = (float*)alloc((size_t)N * 4 * 4);
    float* alsrc2 = (float*)alloc((size_t)N * 4 * 4);
    float* aldst2 = (float*)alloc((size_t)N * 4 * 4);
    float* was    = (float*)alloc(256 * 4);
    float* wad    = (float*)alloc(256 * 4);
    uint2* wkg    = (uint2*)alloc(2048 * 8);
    int* cnt  = (int*)alloc((size_t)N * 4);
    int* rp   = (int*)alloc((size_t)N * 4);
    int* curA = (int*)alloc(256 * 4);
    int* bc   = (int*)alloc(256 * 4);
    int* bb   = (int*)alloc(260 * 4);
    int* srccol = (int*)alloc((size_t)E * 4);

    int nbk = (N + 511) >> 9;       // 512-node buckets
    int ntilesA = (E + TILE - 1) / TILE;
    int nt1 = (N + 63) >> 6;        // 64-row GEMM tiles

    prew_k<<<1, 256, 0, stream>>>(W2, as2, ad2, was, wad, wkg);
    hipMemsetAsync(bc, 0, 256 * 4, stream);
    bhist_k<<<512, 256, 0, stream>>>(ei, bc, E, nbk);
    bscan_k<<<1, 256, 0, stream>>>(bc, bb, curA, nbk);
    partA_k<<<ntilesA, 256, 0, stream>>>(ei, curA, pairs, E, nbk);
    partB2_k<<<nbk, 256, 0, stream>>>(pairs, bb, rp, cnt, srccol, N);

    gemm1_k<<<nt1, 256, 0, stream>>>(x, W1, as1, ad1, h1h, alsrc1, aldst1, N);
    node1_k<<<(N + 15) / 16, 256, 0, stream>>>(h1h, srccol, alsrc1, aldst1, rp, cnt, b1,
                                               was, wad, h1o, alsrc2, aldst2, N);
    node2_k<<<(N + 15) / 16, 256, 0, stream>>>(h1o, srccol, alsrc2, aldst2, rp, cnt,
                                               wkg, b2, out, N);
}